// Round 1
// baseline (343.561 us; speedup 1.0000x reference)
//
#include <hip/hip_runtime.h>
#include <hip/hip_bf16.h>
#include <float.h>

#define NB 32
#define NBCE 32
#define L 128
#define NT 1024
#define R 132                      /* row stride of mirror-square */
#define PAD 160                    /* tail pad: masked overreads stay in-bounds */
#define LOGMIN -87.49823f          /* ln(1e-38) */

// ---- mask dtype runtime detection (element [0] is guaranteed true: lens >= 64) ----
__device__ __forceinline__ int mask_mode(const void* p) {
    unsigned int v = ((const unsigned int*)p)[0];
    if (v == 1u) return 1;            // int32 0/1 storage
    if (v == 0x3F800000u) return 2;   // float32 storage
    return 0;                         // byte storage
}
__device__ __forceinline__ bool mask_at(const void* p, int mode, int idx) {
    if (mode == 1) return ((const int*)p)[idx] != 0;
    if (mode == 2) return ((const float*)p)[idx] != 0.0f;
    return ((const unsigned char*)p)[idx] != 0;
}

__device__ __forceinline__ float lse2(float a, float b) {
    return fmaxf(a, b) + log1pf(__expf(-fabsf(a - b)));
}

// ---- DPP butterfly reduce within aligned subgroups of 8 lanes ----
template<int C>
__device__ __forceinline__ float dppf(float x) {
    return __int_as_float(__builtin_amdgcn_mov_dpp(__float_as_int(x), C, 0xF, 0xF, true));
}
__device__ __forceinline__ float bfly8_max(float x) {
    x = fmaxf(x, dppf<0xB1>(x));   // lane^1
    x = fmaxf(x, dppf<0x4E>(x));   // lane^2
    x = fmaxf(x, dppf<0x141>(x));  // row_half_mirror: ^7 within 8
    return x;
}
__device__ __forceinline__ float bfly8_add(float x) {
    x += dppf<0xB1>(x);
    x += dppf<0x4E>(x);
    x += dppf<0x141>(x);
    return x;
}

// masked pair loader: terms t = sub + 8*kk, valid iff lo <= t < hi.
// buf[kk] = p1[t] + p2[t] (or -FLT_MAX), mloc = running max. Pure reads + reg ops.
template<int NUMAX>
__device__ __forceinline__ void load_pairs(float* buf, int sub, int lo, int hi,
                                           const float* p1, const float* p2, float& mloc) {
    p1 += sub; p2 += sub;
#pragma unroll
    for (int kk = 0; kk < NUMAX; kk += 2) {
        if (kk * 8 >= hi) break;
        const int o0 = kk * 8, o1 = o0 + 8;
        float a0 = p1[o0] + p2[o0];
        float a1 = p1[o1] + p2[o1];
        const int t0 = sub + o0, t1 = sub + o1;
        a0 = (t0 >= lo && t0 < hi) ? a0 : -FLT_MAX;
        a1 = (t1 >= lo && t1 < hi) ? a1 : -FLT_MAX;
        buf[kk] = a0; buf[kk + 1] = a1;
        mloc = fmaxf(mloc, fmaxf(a0, a1));
    }
}
template<int NUMAX>
__device__ __forceinline__ void sum_exp8(const float* buf, int hi, float M, float& s) {
#pragma unroll
    for (int kk = 0; kk < NUMAX; kk += 2) {
        if (kk * 8 >= hi) break;
        s += __expf(buf[kk] - M) + __expf(buf[kk + 1] - M);
    }
}

// ================= fused kernel: blocks [0,NB) = per-batch DP; [NB,NB+NBCE) = BCE =================
__global__ __launch_bounds__(NT, 1) void tree_dp_kernel(
    const float* __restrict__ logits,   // [B,L,L,2]
    const int*   __restrict__ spans_ind,// [B,L,L]
    const void*  __restrict__ maskspan, // [B,L,L] bool
    const float* __restrict__ ph, const float* __restrict__ pt,
    const int* __restrict__ ph_ind, const int* __restrict__ pt_ind,
    const void* __restrict__ maskarc,
    double*      __restrict__ ws)
{
    const int tid = threadIdx.x;

    // ---------------- BCE blocks (no LDS use) ----------------
    if (blockIdx.x >= NB) {
        const int mode = mask_mode(maskarc);
        const int tot = NB * L * L;
        double sph = 0.0, spt = 0.0, cnt = 0.0;
        for (int idx = (blockIdx.x - NB) * NT + tid; idx < tot; idx += NBCE * NT) {
            if (mask_at(maskarc, mode, idx)) {
                float x = ph[idx]; float y = (float)ph_ind[idx];
                sph += (double)(fmaxf(x, 0.0f) - x * y + log1pf(__expf(-fabsf(x))));
                x = pt[idx]; y = (float)pt_ind[idx];
                spt += (double)(fmaxf(x, 0.0f) - x * y + log1pf(__expf(-fabsf(x))));
                cnt += 1.0;
            }
        }
        for (int off = 32; off > 0; off >>= 1) {
            sph += __shfl_down(sph, off);
            spt += __shfl_down(spt, off);
            cnt += __shfl_down(cnt, off);
        }
        if ((tid & 63) == 0) {
            atomicAdd(&ws[2], sph); atomicAdd(&ws[3], spt); atomicAdd(&ws[4], cnt);
        }
        return;
    }

    // ---------------- DP blocks ----------------
    // mirror-square: Am[i*R+j] == Am[j*R+i] == alpha[i,j] (i<=j). Same for Gm (gamma).
    // Diagonal/untouched slots hold sc.
    __shared__ float Am[L * R + PAD];
    __shared__ float Gm[L * R + PAD];

    const int b = blockIdx.x;
    const int mbase = b * L * L;
    const int mode = mask_mode(maskspan);

    int pred = (tid < L) && mask_at(maskspan, mode, mbase + tid);
    const int n = __syncthreads_count(pred);

    const float* lg = logits + (size_t)b * L * L * 2;
    const int* si = spans_ind + mbase;

    // ---- init: sc into both mirror halves of Am and Gm ----
    for (int e = tid; e < L * L; e += NT) {
        int ii = e >> 7, jj = e & (L - 1);
        if (ii <= jj && jj < n) {
            const float* p = lg + (size_t)e * 2;
            float v = lse2(p[0], p[1]);
            Am[ii * R + jj] = v; Am[jj * R + ii] = v;
            Gm[ii * R + jj] = v; Gm[jj * R + ii] = v;
        }
    }
    __syncthreads();

    // Persistent row ownership: subgroup of 8 lanes owns row i for ALL widths.
    const int i = tid >> 3;
    const int sub = tid & 7;
    double local = 0.0;
    float buf1[16], buf2[16];

    // ======== INSIDE (software-pipelined) ========
    // alpha[i,j] = sc[i,j] + LSE_t( alpha[i,i+t] + alpha[i+1+t,j] ), t in [0,w)
    // New terms at step w: t=0 (needs alpha[i+1,j], 1 broadcast read) and
    // t=w-1 (left = own previous value pv, right = diag sc[j,j] = rjd prefetched).
    // Bulk t in [1,w-2] prefetched + partially LSE-reduced one interval early.
    float ld0 = 0.f, pv = 0.f, scij = 0.f, rjd = 0.f;
    float m_part = -FLT_MAX, s_part = 0.f;
    if (i < n) ld0 = Am[i * R + i];             // alpha[i,i] = sc diag (broadcast)
    if (i < n - 1) scij = Am[i * R + i + 1];    // sc of first cell (w=1)

    for (int w = 1; w < n; ++w) {
        const int c = n - w;
        const int j = i + w;
        // issue the one new-data read first
        float r0 = 0.f;
        if (i < c) r0 = Am[j * R + i + 1];      // alpha[i+1,j] (width w-1, broadcast)
        // ---- prefetch loads for step w+1 (all widths <= w-1: old data) ----
        float nsc = 0.f, nrjd = 0.f, mloc = -FLT_MAX;
        const bool pf = (i < c - 1);
        if (pf) {
            nsc  = Am[i * R + (j + 1)];                 // sc slot of next cell
            nrjd = Am[(j + 1) * R + (j + 1)];           // diag sc[j+1,j+1]
            // pairs: alpha[i,i+t] + alpha[i+1+t, j+1], t in [1, w-1]
            load_pairs<16>(buf1, sub, 1, w, &Am[i * R + i], &Am[(j + 1) * R + i + 1], mloc);
        }
        // ---- finish step w (short post-barrier chain) ----
        if (i < c) {
            float ta = ld0 + r0;
            float tb = (w >= 2) ? (pv + rjd) : -FLT_MAX;
            float M = fmaxf(fmaxf(m_part, ta), tb);
            float S = s_part * __expf(m_part - M) + __expf(ta - M) + __expf(tb - M);
            float val = scij + M + __logf(S);
            if (sub == 0) { Am[i * R + j] = val; Am[j * R + i] = val; }
            pv = val;
        }
        // ---- prefetch reduce (pre-barrier) ----
        m_part = -FLT_MAX; s_part = 0.f;
        if (pf) {
            float Mp = bfly8_max(mloc);
            float s = 0.f;
            sum_exp8<16>(buf1, w, Mp, s);
            s_part = bfly8_add(s);
            m_part = Mp;
            scij = nsc; rjd = nrjd;
        }
        __syncthreads();
    }

    const float logZ = Am[n - 1];   // alpha[0, n-1]

    // ======== OUTSIDE (software-pipelined), widths n-2 .. 0 ========
    // gamma[i,j] = sc[i,j] + LSE( k>j: gamma[i,k]+alpha[j+1,k] ; k<i: gamma[k,j]+alpha[k,i-1] )
    // New terms at step w: k=j+1 (gamma[i,j+1] = own pv, + diag alpha[j+1,j+1] = adJ) and
    // k=i-1 (gamma[i-1,j]: 1 broadcast read, + diag alpha[i-1,i-1] = adI, per-row constant).
    // Bulk (k >= j+2 and k <= i-2) prefetched one interval early.
    // w = 0 computes beta_ii = LSE(...) (no sc) and emits the diagonal loss.
    float adI = 0.f, adJ = 0.f, scO = 0.f;
    if (i >= 1 && i < n) adI = Am[(i - 1) * R + (i - 1)];
    if (i == 0) pv = Gm[n - 1];     // gamma[0,n-1] = sc (never updated)

    // prologue prefetch for w = n-2
    m_part = -FLT_MAX; s_part = 0.f;
    {
        const int w1 = n - 2;
        if (i < n - w1) {
            const int j1 = i + w1;
            scO = Gm[i * R + j1];
            if (j1 < n - 1) adJ = Am[(j1 + 1) * R + (j1 + 1)];
            const int nt1 = n - 1 - j1;
            float mloc = -FLT_MAX;
            load_pairs<16>(buf1, sub, 1, nt1, &Gm[i * R + j1 + 1], &Am[(j1 + 1) * R + j1 + 1], mloc);
            load_pairs<16>(buf2, sub, 0, i - 1, &Gm[j1 * R], &Am[(i - 1) * R], mloc);
            float Mp = bfly8_max(mloc);
            float s = 0.f;
            sum_exp8<16>(buf1, nt1, Mp, s);
            sum_exp8<16>(buf2, i - 1, Mp, s);
            s_part = bfly8_add(s);
            m_part = Mp;
        }
    }

    for (int w = n - 2; w >= 0; --w) {
        const int c = n - w;
        const int j = i + w;
        // issue the one new-data read first
        float r0g = 0.f;
        if (i < c && i >= 1) r0g = Gm[j * R + (i - 1)];   // gamma[i-1,j] (width w+1, broadcast)
        // ---- prefetch loads for step w-1 (all widths >= w+1: old data) ----
        float nsc = 0.f, nadJ = 0.f, mloc = -FLT_MAX;
        const bool pf = (w >= 1) && (i < c + 1);
        int nt1 = 0;
        if (pf) {
            const int j1 = i + w - 1;
            nsc = Gm[i * R + j1];
            if (j1 < n - 1) nadJ = Am[(j1 + 1) * R + (j1 + 1)];
            nt1 = n - 1 - j1;
            // g1 bulk: gamma[i,k]+alpha[j1+1,k], k = j1+1+t, t in [1, nt1)
            load_pairs<16>(buf1, sub, 1, nt1, &Gm[i * R + j1 + 1], &Am[(j1 + 1) * R + j1 + 1], mloc);
            // g2 bulk: gamma[k,j1]+alpha[k,i-1], k = t in [0, i-1)
            load_pairs<16>(buf2, sub, 0, i - 1, &Gm[j1 * R], &Am[(i - 1) * R], mloc);
        }
        // ---- finish step w ----
        if (i < c) {
            float g1n = (j < n - 1) ? (pv + adJ) : -FLT_MAX;
            float g2n = (i >= 1) ? (r0g + adI) : -FLT_MAX;
            float M = fmaxf(fmaxf(m_part, g1n), g2n);
            float S = s_part * __expf(m_part - M) + __expf(g1n - M) + __expf(g2n - M);
            if (w >= 1) {
                float val = scO + M + __logf(S);
                if (sub == 0) { Gm[i * R + j] = val; Gm[j * R + i] = val; }
                pv = val;
            } else if (sub == 0) {
                float beta_ii = M + __logf(S);
                const float* p = lg + ((size_t)i * L + i) * 2;
                float lc = (si[i * L + i] == 2) ? p[1] : p[0];
                // log marg(diag) = beta_ii - logZ + l_c  (alpha_ii == sc_ii cancels)
                local += (double)fmaxf(beta_ii - logZ + lc, LOGMIN);
            }
        }
        // ---- prefetch reduce ----
        m_part = -FLT_MAX; s_part = 0.f;
        if (pf) {
            float Mp = bfly8_max(mloc);
            float s = 0.f;
            sum_exp8<16>(buf1, nt1, Mp, s);
            sum_exp8<16>(buf2, i - 1, Mp, s);
            s_part = bfly8_add(s);
            m_part = Mp;
            scO = nsc; adJ = nadJ;
        }
        __syncthreads();
    }

    // ---- strict-upper loss ----
    for (int e = tid; e < L * L; e += NT) {
        int ii = e >> 7, jj = e & (L - 1);
        if (ii < jj && jj < n) {
            const float* p = lg + (size_t)e * 2;
            float a = p[0], cc = p[1];
            float sc = lse2(a, cc);
            float lc = (si[e] == 2) ? cc : a;
            // log marg = alpha + (gamma - sc) - logZ + l_c - sc
            float logm = Am[ii * R + jj] + Gm[ii * R + jj] - logZ + lc - 2.0f * sc;
            local += (double)fmaxf(logm, LOGMIN);
        }
    }

    // wave reduce + one atomic per wave
    for (int off = 32; off > 0; off >>= 1)
        local += __shfl_down(local, off);
    if ((tid & 63) == 0) atomicAdd(&ws[0], local);
    if (tid == 0) atomicAdd(&ws[1], (double)n);
}

// ================= finalize =================
__global__ void finalize_kernel(const double* __restrict__ ws, float* __restrict__ out) {
    double loss_spans = -ws[0] / ws[1];
    double bce = (ws[2] + ws[3]) / ws[4];
    out[0] = (float)(0.5 * loss_spans + 0.5 * bce);
}

extern "C" void kernel_launch(void* const* d_in, const int* in_sizes, int n_in,
                              void* d_out, int out_size, void* d_ws, size_t ws_size,
                              hipStream_t stream) {
    (void)in_sizes; (void)n_in; (void)out_size; (void)ws_size;
    const float* span_logits = (const float*)d_in[0];
    const float* ph          = (const float*)d_in[1];
    const float* pt          = (const float*)d_in[2];
    /* d_in[3] = ph_arc: unused by reference */
    const int*   spans_ind   = (const int*)d_in[4];
    const int*   ph_ind      = (const int*)d_in[5];
    const int*   pt_ind      = (const int*)d_in[6];
    const void*  maskspan    = d_in[7];
    const void*  maskarc     = d_in[8];
    double* ws = (double*)d_ws;
    float* out = (float*)d_out;

    hipMemsetAsync(d_ws, 0, 5 * sizeof(double), stream);
    hipLaunchKernelGGL(tree_dp_kernel, dim3(NB + NBCE), dim3(NT), 0, stream,
                       span_logits, spans_ind, maskspan,
                       ph, pt, ph_ind, pt_ind, maskarc, ws);
    hipLaunchKernelGGL(finalize_kernel, dim3(1), dim3(1), 0, stream, ws, out);
}

// Round 2
// 343.552 us; speedup vs baseline: 1.0000x; 1.0000x over previous
//
#include <hip/hip_runtime.h>
#include <float.h>

#define NB 32
#define NBCE 32
#define L 128
#define NT 1024
#define R 132                      /* row stride (dwords); 132=33*16B -> every row base 16B-aligned; 132%32=4 staggers banks */
#define PAD 8
#define LOGMIN -87.49823f          /* ln(1e-38) */

// ---- mask dtype runtime detection (element [0] is guaranteed true: lens >= 64) ----
__device__ __forceinline__ int mask_mode(const void* p) {
    unsigned int v = ((const unsigned int*)p)[0];
    if (v == 1u) return 1;            // int32 0/1 storage
    if (v == 0x3F800000u) return 2;   // float32 storage
    return 0;                         // byte storage
}
__device__ __forceinline__ bool mask_at(const void* p, int mode, int idx) {
    if (mode == 1) return ((const int*)p)[idx] != 0;
    if (mode == 2) return ((const float*)p)[idx] != 0.0f;
    return ((const unsigned char*)p)[idx] != 0;
}

__device__ __forceinline__ float lse2(float a, float b) {
    return fmaxf(a, b) + log1pf(__expf(-fabsf(a - b)));
}

// ---- DPP butterfly reduce within aligned subgroups of 8 or 16 lanes ----
template<int C>
__device__ __forceinline__ float dppf(float x) {
    return __int_as_float(__builtin_amdgcn_mov_dpp(__float_as_int(x), C, 0xF, 0xF, true));
}
template<int T>
__device__ __forceinline__ float bfly_max(float x) {
    x = fmaxf(x, dppf<0xB1>(x));   // lane^1
    x = fmaxf(x, dppf<0x4E>(x));   // lane^2
    x = fmaxf(x, dppf<0x141>(x));  // row_half_mirror: ^7 within 8
    if (T == 16) x = fmaxf(x, dppf<0x140>(x)); // row_mirror: ^15 within 16
    return x;
}
template<int T>
__device__ __forceinline__ float bfly_add(float x) {
    x += dppf<0xB1>(x);
    x += dppf<0x4E>(x);
    x += dppf<0x141>(x);
    if (T == 16) x += dppf<0x140>(x);
    return x;
}

// ---- aligned 16B col-block loader ----
// Terms are indexed by absolute column c in [clo, chi); both streams p1,p2 are row
// bases (16B-aligned). Lane sub of a T-subgroup handles col-blocks kb0+sub+T*m.
// Out-of-range elements -> -FLT_MAX (exp later gives exact 0).
template<int T, int M>
__device__ __forceinline__ void load_blk(float4* buf, int sub, int clo, int chi,
                                         const float* p1, const float* p2, float& mloc) {
    const int kb0 = clo >> 2;
#pragma unroll
    for (int m = 0; m < M; ++m) {
        const int c0 = (kb0 + sub + T * m) << 2;
        if (c0 >= chi) break;
        const float4 a = *(const float4*)(p1 + c0);
        const float4 b = *(const float4*)(p2 + c0);
        const unsigned rng = (unsigned)(chi - clo);
        float4 v;
        v.x = ((unsigned)(c0 + 0 - clo) < rng) ? a.x + b.x : -FLT_MAX;
        v.y = ((unsigned)(c0 + 1 - clo) < rng) ? a.y + b.y : -FLT_MAX;
        v.z = ((unsigned)(c0 + 2 - clo) < rng) ? a.z + b.z : -FLT_MAX;
        v.w = ((unsigned)(c0 + 3 - clo) < rng) ? a.w + b.w : -FLT_MAX;
        buf[m] = v;
        mloc = fmaxf(mloc, fmaxf(fmaxf(v.x, v.y), fmaxf(v.z, v.w)));
    }
}
template<int T, int M>
__device__ __forceinline__ void sumexp_blk(const float4* buf, int sub, int clo, int chi,
                                           float Mv, float& s) {
    const int kb0 = clo >> 2;
#pragma unroll
    for (int m = 0; m < M; ++m) {
        const int c0 = (kb0 + sub + T * m) << 2;
        if (c0 >= chi) break;
        const float4 v = buf[m];
        s += __expf(v.x - Mv) + __expf(v.y - Mv) + __expf(v.z - Mv) + __expf(v.w - Mv);
    }
}

// ================= fused kernel: blocks [0,NB) = per-batch DP; [NB,NB+NBCE) = BCE =================
__global__ __launch_bounds__(NT, 1) void tree_dp_kernel(
    const float* __restrict__ logits,   // [B,L,L,2]
    const int*   __restrict__ spans_ind,// [B,L,L]
    const void*  __restrict__ maskspan, // [B,L,L] bool
    const float* __restrict__ ph, const float* __restrict__ pt,
    const int* __restrict__ ph_ind, const int* __restrict__ pt_ind,
    const void* __restrict__ maskarc,
    double*      __restrict__ ws)
{
    const int tid = threadIdx.x;

    // ---------------- BCE blocks (no LDS use) ----------------
    if (blockIdx.x >= NB) {
        const int mode = mask_mode(maskarc);
        const int tot = NB * L * L;
        double sph = 0.0, spt = 0.0, cnt = 0.0;
        for (int idx = (blockIdx.x - NB) * NT + tid; idx < tot; idx += NBCE * NT) {
            if (mask_at(maskarc, mode, idx)) {
                float x = ph[idx]; float y = (float)ph_ind[idx];
                sph += (double)(fmaxf(x, 0.0f) - x * y + log1pf(__expf(-fabsf(x))));
                x = pt[idx]; y = (float)pt_ind[idx];
                spt += (double)(fmaxf(x, 0.0f) - x * y + log1pf(__expf(-fabsf(x))));
                cnt += 1.0;
            }
        }
        for (int off = 32; off > 0; off >>= 1) {
            sph += __shfl_down(sph, off);
            spt += __shfl_down(spt, off);
            cnt += __shfl_down(cnt, off);
        }
        if ((tid & 63) == 0) {
            atomicAdd(&ws[2], sph); atomicAdd(&ws[3], spt); atomicAdd(&ws[4], cnt);
        }
        return;
    }

    // ---------------- DP blocks ----------------
    // Am upper [i][j] (i<=j): alpha[i,j].  Am lower, DURING INSIDE (shifted):
    //   Am[j][k] = alpha[k+1, j]  -> inside's both streams index the SAME cols [i,j).
    // After inside a reshift pass converts lower to unshifted Am[j][k] = alpha[k, j].
    // Gm: unshifted mirror of gamma (diag/untouched slots hold sc).
    __shared__ __align__(16) float Am[L * R + PAD];
    __shared__ __align__(16) float Gm[L * R + PAD];

    const int b = blockIdx.x;
    const int mbase = b * L * L;
    const int mode = mask_mode(maskspan);

    int predv = (tid < L) && mask_at(maskspan, mode, mbase + tid);
    const int n = __syncthreads_count(predv);

    const float* lg = logits + (size_t)b * L * L * 2;
    const int* si = spans_ind + mbase;

    // ---- init: sc into upper + SHIFTED lower of Am; both halves of Gm ----
    for (int e = tid; e < L * L; e += NT) {
        int ii = e >> 7, jj = e & (L - 1);
        if (ii <= jj && jj < n) {
            const float* p = lg + (size_t)e * 2;
            float v = lse2(p[0], p[1]);
            Am[ii * R + jj] = v;
            if (ii >= 1) Am[jj * R + ii - 1] = v;   // shifted: [j][k]=alpha[k+1,j], diag at [j][j-1]
            Gm[ii * R + jj] = v; Gm[jj * R + ii] = v;
        }
    }
    __syncthreads();

    // ======== INSIDE ========
    // alpha[i,j] = sc[i,j] + LSE_k( alpha[i,k] + alpha[k+1,j] ), k in [i, j)
    // stream1 = Am row i (upper), stream2 = Am row j (shifted lower) — same cols.
    for (int w = 1; w < n; ++w) {
        const int c = n - w;
        if (c > 64) {                       // T=8, w <= 62 -> M=3
            const int cell = tid >> 3, sub = tid & 7;
            if (cell < c) {
                const int i = cell, j = i + w;
                float4 buf[3]; float mloc = -FLT_MAX;
                load_blk<8, 3>(buf, sub, i, j, &Am[i * R], &Am[j * R], mloc);
                float Mv = bfly_max<8>(mloc);
                float s = 0.0f;
                sumexp_blk<8, 3>(buf, sub, i, j, Mv, s);
                float S = bfly_add<8>(s);
                if (sub == 0) {
                    float val = Am[i * R + j] + Mv + __logf(S);   // slot holds sc
                    Am[i * R + j] = val;
                    Am[j * R + i - 1] = val;  // i=0: scribbles col 131 of row j-1 (never read)
                }
            }
        } else {                            // T=16, w <= 127 -> M=2
            const int cell = tid >> 4, sub = tid & 15;
            if (cell < c) {
                const int i = cell, j = i + w;
                float4 buf[2]; float mloc = -FLT_MAX;
                load_blk<16, 2>(buf, sub, i, j, &Am[i * R], &Am[j * R], mloc);
                float Mv = bfly_max<16>(mloc);
                float s = 0.0f;
                sumexp_blk<16, 2>(buf, sub, i, j, Mv, s);
                float S = bfly_add<16>(s);
                if (sub == 0) {
                    float val = Am[i * R + j] + Mv + __logf(S);
                    Am[i * R + j] = val;
                    Am[j * R + i - 1] = val;
                }
            }
        }
        __syncthreads();
    }

    const float logZ = Am[n - 1];   // alpha[0, n-1] (upper row 0)

    // ---- reshift Am lower: [r][c] = alpha[c, r]  (was alpha[c+1, r] at [r][c]) ----
    {
        float tmp[16];
#pragma unroll
        for (int p = 0; p < 16; ++p) {
            const int e = tid + p * NT;
            const int r = e >> 7, cc = e & (L - 1);
            tmp[p] = 0.0f;
            if (cc < r && r < n)
                tmp[p] = (cc == 0) ? Am[r] : Am[r * R + cc - 1];
        }
        __syncthreads();
#pragma unroll
        for (int p = 0; p < 16; ++p) {
            const int e = tid + p * NT;
            const int r = e >> 7, cc = e & (L - 1);
            if (cc < r && r < n) Am[r * R + cc] = tmp[p];
        }
    }
    __syncthreads();

    // ======== OUTSIDE, widths n-2..1 ========
    // gamma[i,j] = sc[i,j] + LSE( k in (j,n): gamma[i,k]+alpha[j+1,k] ;
    //                             k in [0,i): gamma[k,j]+alpha[k,i-1] )
    // g1: Gm row i (upper) + Am row j+1 (upper), cols [j+1, n)   — same cols.
    // g2: Gm row j (lower) + Am row i-1 (unshifted lower), cols [0, i) — same cols.
    for (int w = n - 2; w >= 1; --w) {
        const int c = n - w;
        if (c > 64) {                       // T=8 -> M=4,4
            const int cell = tid >> 3, sub = tid & 7;
            if (cell < c) {
                const int i = cell, j = i + w;
                float4 b1[4], b2[4]; float mloc = -FLT_MAX;
                load_blk<8, 4>(b1, sub, j + 1, n, &Gm[i * R], &Am[(j + 1) * R], mloc);
                const float* pa2 = &Am[(i >= 1 ? i - 1 : 0) * R];
                load_blk<8, 4>(b2, sub, 0, i, &Gm[j * R], pa2, mloc);
                float Mv = bfly_max<8>(mloc);
                float s = 0.0f;
                sumexp_blk<8, 4>(b1, sub, j + 1, n, Mv, s);
                sumexp_blk<8, 4>(b2, sub, 0, i, Mv, s);
                float S = bfly_add<8>(s);
                if (sub == 0) {
                    float val = Gm[i * R + j] + Mv + __logf(S);   // slot holds sc
                    Gm[i * R + j] = val; Gm[j * R + i] = val;
                }
            }
        } else {                            // T=16 -> M=2,1
            const int cell = tid >> 4, sub = tid & 15;
            if (cell < c) {
                const int i = cell, j = i + w;
                float4 b1[2], b2[1]; float mloc = -FLT_MAX;
                load_blk<16, 2>(b1, sub, j + 1, n, &Gm[i * R], &Am[(j + 1) * R], mloc);
                const float* pa2 = &Am[(i >= 1 ? i - 1 : 0) * R];
                load_blk<16, 1>(b2, sub, 0, i, &Gm[j * R], pa2, mloc);
                float Mv = bfly_max<16>(mloc);
                float s = 0.0f;
                sumexp_blk<16, 2>(b1, sub, j + 1, n, Mv, s);
                sumexp_blk<16, 1>(b2, sub, 0, i, Mv, s);
                float S = bfly_add<16>(s);
                if (sub == 0) {
                    float val = Gm[i * R + j] + Mv + __logf(S);
                    Gm[i * R + j] = val; Gm[j * R + i] = val;
                }
            }
        }
        __syncthreads();
    }

    // ---- fused w=0 outside (beta_ii) + diagonal loss ----
    double local = 0.0;
    {
        const int cell = tid >> 3, sub = tid & 7;   // T=8 -> M=4,4
        if (cell < n) {
            const int i = cell;
            float4 b1[4], b2[4]; float mloc = -FLT_MAX;
            const float* pa1 = &Am[(i + 1 < n ? i + 1 : 0) * R];
            load_blk<8, 4>(b1, sub, i + 1, n, &Gm[i * R], pa1, mloc);
            const float* pa2 = &Am[(i >= 1 ? i - 1 : 0) * R];
            load_blk<8, 4>(b2, sub, 0, i, &Gm[i * R], pa2, mloc);
            float Mv = bfly_max<8>(mloc);
            float s = 0.0f;
            sumexp_blk<8, 4>(b1, sub, i + 1, n, Mv, s);
            sumexp_blk<8, 4>(b2, sub, 0, i, Mv, s);
            float S = bfly_add<8>(s);
            if (sub == 0) {
                float beta_ii = Mv + __logf(S);
                const float* p = lg + ((size_t)i * L + i) * 2;
                float lc = (si[i * L + i] == 2) ? p[1] : p[0];
                // log marg(diag) = beta_ii - logZ + l_c  (alpha_ii == sc_ii cancels)
                local += (double)fmaxf(beta_ii - logZ + lc, LOGMIN);
            }
        }
    }

    // ---- strict-upper loss ----
    for (int e = tid; e < L * L; e += NT) {
        int ii = e >> 7, jj = e & (L - 1);
        if (ii < jj && jj < n) {
            const float* p = lg + (size_t)e * 2;
            float a = p[0], cc = p[1];
            float sc = lse2(a, cc);
            float lc = (si[e] == 2) ? cc : a;
            // log marg = alpha + (gamma - sc) - logZ + l_c - sc
            float logm = Am[ii * R + jj] + Gm[ii * R + jj] - logZ + lc - 2.0f * sc;
            local += (double)fmaxf(logm, LOGMIN);
        }
    }

    // wave reduce + one atomic per wave
    for (int off = 32; off > 0; off >>= 1)
        local += __shfl_down(local, off);
    if ((tid & 63) == 0) atomicAdd(&ws[0], local);
    if (tid == 0) atomicAdd(&ws[1], (double)n);
}

// ================= finalize =================
__global__ void finalize_kernel(const double* __restrict__ ws, float* __restrict__ out) {
    double loss_spans = -ws[0] / ws[1];
    double bce = (ws[2] + ws[3]) / ws[4];
    out[0] = (float)(0.5 * loss_spans + 0.5 * bce);
}

extern "C" void kernel_launch(void* const* d_in, const int* in_sizes, int n_in,
                              void* d_out, int out_size, void* d_ws, size_t ws_size,
                              hipStream_t stream) {
    (void)in_sizes; (void)n_in; (void)out_size; (void)ws_size;
    const float* span_logits = (const float*)d_in[0];
    const float* ph          = (const float*)d_in[1];
    const float* pt          = (const float*)d_in[2];
    /* d_in[3] = ph_arc: unused by reference */
    const int*   spans_ind   = (const int*)d_in[4];
    const int*   ph_ind      = (const int*)d_in[5];
    const int*   pt_ind      = (const int*)d_in[6];
    const void*  maskspan    = d_in[7];
    const void*  maskarc     = d_in[8];
    double* ws = (double*)d_ws;
    float* out = (float*)d_out;

    hipMemsetAsync(d_ws, 0, 5 * sizeof(double), stream);
    hipLaunchKernelGGL(tree_dp_kernel, dim3(NB + NBCE), dim3(NT), 0, stream,
                       span_logits, spans_ind, maskspan,
                       ph, pt, ph_ind, pt_ind, maskarc, ws);
    hipLaunchKernelGGL(finalize_kernel, dim3(1), dim3(1), 0, stream, ws, out);
}